// Round 4
// baseline (458.953 us; speedup 1.0000x reference)
//
#include <hip/hip_runtime.h>

// GraphProbeFeatures: B=128, N=4096, H=128, D_OUT=3, P=128.
// Inputs proven fp32 (round-3 NaN elimination); runtime dtype probe kept as
// insurance (ln_g all-ones: first word 0x3F800000 fp32 vs 0x3F803F80 bf16).
// OUTPUT: fp32 (reference's output dtype per harness doc) -- round-3 fix.
// k_prep: pw -> pwT bf16 [4][128][4096] in ws (+ xbuf fp32 copy of inputs).
// k_main: one block per b, fully fused SIREN + 4 projections (MFMA 16x16x32
// bf16) + in-kernel LayerNorm. h3 folded: z3 = W2^T.y + b2*S3.
// ws: pwT 4 MB + xbuf 32 KB.

typedef unsigned short u16;
typedef __attribute__((ext_vector_type(8))) short short8;   // 8 bf16 (4 VGPR)
typedef __attribute__((ext_vector_type(4))) short short4v;
typedef __attribute__((ext_vector_type(4))) float f32x4;

#define DEV __device__ __forceinline__

DEV float b2f(u16 h){ return __uint_as_float(((unsigned)h) << 16); }
DEV u16 f2b(float f){
  unsigned u = __float_as_uint(f);
  return (u16)((u + 0x7FFFu + ((u >> 16) & 1u)) >> 16);  // RNE
}
DEV float sin_fast(float x){
  float r = x * 0.15915494309189535f;   // radians -> revolutions
  r = r - rintf(r);                     // [-0.5, 0.5]
#if __has_builtin(__builtin_amdgcn_sinf)
  return __builtin_amdgcn_sinf(r);      // v_sin_f32 (input in revolutions)
#else
  return __sinf(r * 6.283185307179586f);
#endif
}
template<int C> DEV float dpp_add(float x){
  int yi = __builtin_amdgcn_update_dpp(0, __float_as_int(x), C, 0xF, 0xF, true);
  return x + __int_as_float(yi);
}
DEV float sum16(float x){                // total over the 16-lane DPP row
  x = dpp_add<0x128>(x);  // row_ror:8
  x = dpp_add<0x124>(x);  // row_ror:4
  x = dpp_add<0x122>(x);  // row_ror:2
  x = dpp_add<0x121>(x);  // row_ror:1
  return x;
}

DEV int is_bf16_fmt(const void* lng){ return *(const unsigned*)lng == 0x3F803F80u; }
struct In {
  const float* f; const u16* h; int bf;
  DEV In(const void* p, int b_) : f((const float*)p), h((const u16*)p), bf(b_) {}
  DEV float at(size_t i) const { return bf ? b2f(h[i]) : f[i]; }
};

// ---------- k_prep: pw -> pwT bf16 [4][128][4096]; block 256: xbuf fp32 ------
__global__ __launch_bounds__(256) void k_prep(const void* pwv, const void* inpv,
                                              const void* lngv,
                                              u16* __restrict__ pwT,
                                              float* __restrict__ xbuf){
  const int bf = is_bf16_fmt(lngv);
  const int t = threadIdx.x;
  if (blockIdx.x == 256){
    In inp(inpv, bf);
    for (int i = t; i < 8192; i += 256) xbuf[i] = inp.at(i);
    return;
  }
  In pw(pwv, bf);
  __shared__ u16 tile[64 * 129];
  const int layer = blockIdx.x >> 6;
  const int n0 = (blockIdx.x & 63) * 64;
  const size_t base = ((size_t)layer * 4096 + n0) * 128;
#pragma unroll
  for (int k = 0; k < 32; k++){
    int idx = k * 256 + t, n = idx >> 7, p = idx & 127;
    tile[n * 129 + p] = f2b(pw.at(base + (size_t)n * 128 + p));
  }
  __syncthreads();
  u16* dst = pwT + (size_t)layer * 128 * 4096 + n0;
#pragma unroll
  for (int k = 0; k < 32; k++){
    int idx = k * 256 + t, p = idx >> 6, n = idx & 63;
    dst[(size_t)p * 4096 + n] = tile[n * 129 + p];
  }
}

// ---------- k_main: fully fused ----------
#define S_NK 136   // [n][h] row stride (272 B, 16B-aligned)
#define S_T  40    // [x][n] row stride (80 B, 16B-aligned)

__global__ __launch_bounds__(512, 2)
void k_main(const void* w0v, const void* w1v, const void* w2v,
            const void* b0v, const void* b1v, const void* b2v,
            const void* pbv, const void* lgv, const void* lbv,
            const u16* __restrict__ pwTg, const float* __restrict__ xbuf,
            float* __restrict__ out){
  __shared__ float sW2[512];          // [128][4], col 3 zero
  __shared__ float sb2[4];
  __shared__ float sPB[512], sG[512], sBB[512];
  __shared__ __align__(16) u16 sh1nk[32 * S_NK];  // h1 [n][h]
  __shared__ __align__(16) u16 sh1T[128 * S_T];   // h1^T [h][n]
  __shared__ __align__(16) u16 sh2T[128 * S_T];   // h2^T [h][n]
  __shared__ __align__(16) u16 sxT[16 * S_T];     // x^T [d][n], rows 2..15 zero
  __shared__ __align__(16) u16 spwA[128 * S_T];   // pw tiles, double-buffered
  __shared__ __align__(16) u16 spwB[128 * S_T];

  // epilogue aliases (only touched after the nt-loop's final barrier)
  float* sP1 = (float*)sh1nk;            // 261*8 fp32 = 8352 B <= 8704
  float* sP2 = (float*)sh1T;             // 8352 <= 10240
  float* sM  = (float*)sh2T;             // 261 fp32
  float* sI  = (float*)sh2T + 512;       // 3092 B <= 10240

  const int bf = is_bf16_fmt(lgv);
  In w0(w0v, bf), w1(w1v, bf), w2(w2v, bf), b0(b0v, bf), b1(b1v, bf),
     b2(b2v, bf), pb(pbv, bf), lg(lgv, bf), lb(lbv, bf);

  const int t = threadIdx.x, b = blockIdx.x;
  const int lane = t & 63, wave = t >> 6, quad = lane >> 4, r16 = lane & 15;
  const int oo = wave * 16 + r16;        // this lane's p-column / h2-unit

  // ---- one-time staging ----
  if (t >= 256 && t < 384){
    int i = t - 256;
    sW2[i * 4 + 0] = w2.at(((size_t)b * 128 + i) * 3 + 0);
    sW2[i * 4 + 1] = w2.at(((size_t)b * 128 + i) * 3 + 1);
    sW2[i * 4 + 2] = w2.at(((size_t)b * 128 + i) * 3 + 2);
    sW2[i * 4 + 3] = 0.f;
  }
  if (t < 4) sb2[t] = (t < 3) ? b2.at(b * 3 + t) : 0.f;
  sPB[t] = pb.at(t); sG[t] = lg.at(t); sBB[t] = lb.at(t);
  for (int k = t; k < 16 * S_T; k += 512) sxT[k] = 0;

  // pass-1 W0 rows in registers: thread computes h = p1hb..+7 for n = p1n
  const int p1n = t >> 4, p1hb = (t & 15) * 8;
  float w00[8], w01[8], b00[8];
#pragma unroll
  for (int j = 0; j < 8; j++){
    w00[j] = w0.at((size_t)b * 256 + p1hb + j);
    w01[j] = w0.at((size_t)b * 256 + 128 + p1hb + j);
    b00[j] = b0.at((size_t)b * 128 + p1hb + j);
  }
  // pass-2: thread computes h = p2h for n = p2nb..+7
  const int p2h = t & 127, p2nb = (t >> 7) * 8;
  const float q00 = w0.at((size_t)b * 256 + p2h);
  const float q01 = w0.at((size_t)b * 256 + 128 + p2h);
  const float qb0 = b0.at((size_t)b * 128 + p2h);
  const float bias1 = b1.at((size_t)b * 128 + oo);

  // W1^T B-fragments (register-resident): B[k=quad*8+j][col ~ oo]
  short8 w1f[4];
#pragma unroll
  for (int ks = 0; ks < 4; ks++){
#pragma unroll
    for (int j = 0; j < 8; j++)
      w1f[ks][j] = (short)f2b(w1.at((size_t)b * 16384 +
                                    (size_t)(ks * 32 + quad * 8 + j) * 128 + oo));
  }
  // ones-row A fragment (row 0 = 1.0) for S3 = sum_n pw3[n][p]
  short8 a1s = {0,0,0,0,0,0,0,0};
  if (r16 == 0){
#pragma unroll
    for (int j = 0; j < 8; j++) a1s[j] = (short)0x3F80;
  }

  const f32x4 zz = {0.f,0.f,0.f,0.f};
  f32x4 az1[8], az2[8], ay[8], az0 = zz, az3 = zz;
#pragma unroll
  for (int i = 0; i < 8; i++){ az1[i] = zz; az2[i] = zz; ay[i] = zz; }

  __syncthreads();

  for (int nt = 0; nt < 128; nt++){
    const int n0 = nt * 32;
    auto stage = [&](int layer, u16* dst){
      int pp = t >> 2, q = t & 3;
      *(short8*)&dst[pp * S_T + q * 8] =
        *(const short8*)(pwTg + ((size_t)(layer * 128 + pp)) * 4096 + n0 + q * 8);
    };

    // ---- Phase A: x stage, h1 both layouts, pw0 -> spwA ----
    if (t < 64){
      int n = t >> 1, c = t & 1;
      sxT[c * S_T + n] = f2b(xbuf[(size_t)(n0 + n) * 2 + c]);
    }
    {
      float x0 = xbuf[(size_t)(n0 + p1n) * 2];
      float x1 = xbuf[(size_t)(n0 + p1n) * 2 + 1];
      short8 v;
#pragma unroll
      for (int j = 0; j < 8; j++)
        v[j] = (short)f2b(sin_fast(30.f * fmaf(x1, w01[j], fmaf(x0, w00[j], b00[j]))));
      *(short8*)&sh1nk[p1n * S_NK + p1hb] = v;
    }
    {
      short8 v;
#pragma unroll
      for (int j = 0; j < 8; j++){
        float x0 = xbuf[(size_t)(n0 + p2nb + j) * 2];
        float x1 = xbuf[(size_t)(n0 + p2nb + j) * 2 + 1];
        v[j] = (short)f2b(sin_fast(30.f * fmaf(x1, q01, fmaf(x0, q00, qb0))));
      }
      *(short8*)&sh1T[p2h * S_T + p2nb] = v;
    }
    stage(0, spwA);
    __syncthreads();

    // ---- Phase B: h2 GEMM + z0 + h2 epilogue -> sh2T; pw1 -> spwB ----
    f32x4 h0 = zz, h1a = zz;
#pragma unroll
    for (int ks = 0; ks < 4; ks++){
      h0  = __builtin_amdgcn_mfma_f32_16x16x32_bf16(
              *(short8*)&sh1nk[r16 * S_NK + ks * 32 + quad * 8], w1f[ks], h0, 0, 0, 0);
      h1a = __builtin_amdgcn_mfma_f32_16x16x32_bf16(
              *(short8*)&sh1nk[(16 + r16) * S_NK + ks * 32 + quad * 8], w1f[ks], h1a, 0, 0, 0);
    }
    {
      short8 bfA = *(short8*)&spwA[oo * S_T + quad * 8];
      az0 = __builtin_amdgcn_mfma_f32_16x16x32_bf16(
              *(short8*)&sxT[r16 * S_T + quad * 8], bfA, az0, 0, 0, 0);
    }
    {
      short4v v;
#pragma unroll
      for (int r = 0; r < 4; r++) v[r] = (short)f2b(sin_fast(30.f * (h0[r] + bias1)));
      *(short4v*)&sh2T[oo * S_T + quad * 4] = v;
#pragma unroll
      for (int r = 0; r < 4; r++) v[r] = (short)f2b(sin_fast(30.f * (h1a[r] + bias1)));
      *(short4v*)&sh2T[oo * S_T + 16 + quad * 4] = v;
    }
    stage(1, spwB);
    __syncthreads();

    // ---- Phase C: z1 (A = sh1T, B = pw1); pw2 -> spwA ----
    {
      short8 bfr = *(short8*)&spwB[oo * S_T + quad * 8];
#pragma unroll
      for (int mb = 0; mb < 8; mb++)
        az1[mb] = __builtin_amdgcn_mfma_f32_16x16x32_bf16(
                    *(short8*)&sh1T[(mb * 16 + r16) * S_T + quad * 8], bfr, az1[mb], 0, 0, 0);
    }
    stage(2, spwA);
    __syncthreads();

    // ---- Phase D: z2 (A = sh2T, B = pw2); pw3 -> spwB ----
    {
      short8 bfr = *(short8*)&spwA[oo * S_T + quad * 8];
#pragma unroll
      for (int mb = 0; mb < 8; mb++)
        az2[mb] = __builtin_amdgcn_mfma_f32_16x16x32_bf16(
                    *(short8*)&sh2T[(mb * 16 + r16) * S_T + quad * 8], bfr, az2[mb], 0, 0, 0);
    }
    stage(3, spwB);
    __syncthreads();

    // ---- Phase E: y (A = sh2T, B = pw3) + S3 ----
    {
      short8 bfr = *(short8*)&spwB[oo * S_T + quad * 8];
#pragma unroll
      for (int mb = 0; mb < 8; mb++)
        ay[mb] = __builtin_amdgcn_mfma_f32_16x16x32_bf16(
                   *(short8*)&sh2T[(mb * 16 + r16) * S_T + quad * 8], bfr, ay[mb], 0, 0, 0);
      az3 = __builtin_amdgcn_mfma_f32_16x16x32_bf16(a1s, bfr, az3, 0, 0, 0);
    }
    __syncthreads();
  }

  // ---- epilogue: z3 finalize, LN stats, emit ----
  const int p = oo;
  float S3 = (quad == 0) ? az3[0] : 0.f;
  S3 += __shfl_xor(S3, 16, 64); S3 += __shfl_xor(S3, 32, 64);
  float z3v[3];
#pragma unroll
  for (int d = 0; d < 3; d++){
    float a = 0.f;
#pragma unroll
    for (int mb = 0; mb < 8; mb++)
#pragma unroll
      for (int r = 0; r < 4; r++)
        a = fmaf(sW2[(mb * 16 + quad * 4 + r) * 4 + d], ay[mb][r], a);
    a += __shfl_xor(a, 16, 64); a += __shfl_xor(a, 32, 64);
    z3v[d] = a + sb2[d] * S3;
  }

  const float pb0v = sPB[p],       pb1v = sPB[128 + p];
  const float pb2v = sPB[256 + p], pb3v = sPB[384 + p];

  auto rowsum = [&](float v, int row, bool wr){
    float s1 = sum16(v), s2 = sum16(v * v);
    if (wr && r16 == 0){ sP1[row * 8 + wave] = s1; sP2[row * 8 + wave] = s2; }
  };
#pragma unroll
  for (int r = 0; r < 2; r++) rowsum(az0[r] + pb0v, r, quad == 0);
#pragma unroll
  for (int mb = 0; mb < 8; mb++)
#pragma unroll
    for (int r = 0; r < 4; r++)
      rowsum(az1[mb][r] + pb1v, 2 + mb * 16 + quad * 4 + r, true);
#pragma unroll
  for (int mb = 0; mb < 8; mb++)
#pragma unroll
    for (int r = 0; r < 4; r++)
      rowsum(az2[mb][r] + pb2v, 130 + mb * 16 + quad * 4 + r, true);
#pragma unroll
  for (int d = 0; d < 3; d++) rowsum(z3v[d] + pb3v, 258 + d, quad == 0);
  __syncthreads();

  if (t < 261){
    float s1 = 0.f, s2 = 0.f;
#pragma unroll
    for (int w = 0; w < 8; w++){ s1 += sP1[t * 8 + w]; s2 += sP2[t * 8 + w]; }
    float m = s1 * (1.f / 128.f);
    float var = fmaf(-m, m, s2 * (1.f / 128.f));
    sM[t] = m;
    sI[t] = rsqrtf(fmaxf(var, 0.f) + 1e-5f);
  }
  __syncthreads();

  const size_t ob = (size_t)b * 261 * 128;
  auto emit = [&](float v, int row, int grp){
    float o = (v - sM[row]) * sI[row] * sG[grp * 128 + p] + sBB[grp * 128 + p];
    out[ob + (size_t)row * 128 + p] = o;   // fp32 output (reference dtype)
  };
  if (quad == 0){
#pragma unroll
    for (int r = 0; r < 2; r++) emit(az0[r] + pb0v, r, 0);
#pragma unroll
    for (int d = 0; d < 3; d++) emit(z3v[d] + pb3v, 258 + d, 3);
  }
#pragma unroll
  for (int mb = 0; mb < 8; mb++)
#pragma unroll
    for (int r = 0; r < 4; r++)
      emit(az1[mb][r] + pb1v, 2 + mb * 16 + quad * 4 + r, 1);
#pragma unroll
  for (int mb = 0; mb < 8; mb++)
#pragma unroll
    for (int r = 0; r < 4; r++)
      emit(az2[mb][r] + pb2v, 130 + mb * 16 + quad * 4 + r, 2);
}

extern "C" void kernel_launch(void* const* d_in, const int* in_sizes, int n_in,
                              void* d_out, int out_size, void* d_ws, size_t ws_size,
                              hipStream_t stream){
  const void* w0  = d_in[0];
  const void* w1  = d_in[1];
  const void* w2  = d_in[2];
  const void* b0  = d_in[3];
  const void* b1  = d_in[4];
  const void* b2  = d_in[5];
  const void* inp = d_in[6];
  const void* pw  = d_in[7];
  const void* pb  = d_in[8];
  const void* lng = d_in[9];
  const void* lnb = d_in[10];
  float* out = (float*)d_out;   // fp32 output (reference's output dtype)

  u16* pwT    = (u16*)d_ws;                                         // 4 MB
  float* xbuf = (float*)((char*)d_ws + (size_t)4 * 128 * 4096 * 2); // 32 KB

  k_prep<<<257, 256, 0, stream>>>(pw, inp, lng, pwT, xbuf);
  k_main<<<128, 512, 0, stream>>>(w0, w1, w2, b0, b1, b2, pb, lng, lnb,
                                  pwT, xbuf, out);
}